// Round 1
// baseline (305.005 us; speedup 1.0000x reference)
//
#include <hip/hip_runtime.h>
#include <hip/hip_bf16.h>
#include <stdint.h>

#define Bv 2
#define Nv 1000
#define Ev 2000
#define Hv 128
#define Mv 4000  // Bv*Ev

typedef __attribute__((ext_vector_type(8))) short bf16x8;
typedef __attribute__((ext_vector_type(4))) float f32x4;
typedef unsigned short u16;
typedef unsigned int u32;

static __device__ __forceinline__ u32 pack2bf(float a, float b) {
  union { __hip_bfloat162 h; u32 u; } c;
  c.h = __float22bfloat162_rn(make_float2(a, b));
  return c.u;
}

// edge_network fp32 [H][H][H] -> bf16, same (h,i,j) layout. 2M elems, 8/thread.
__global__ void k_cvt_en(const float* __restrict__ en, u16* __restrict__ enbf) {
  size_t idx = ((size_t)blockIdx.x * 256u + threadIdx.x) * 8u;
  const f32x4* p = (const f32x4*)(en + idx);
  f32x4 a = p[0], b = p[1];
  uint4 o;
  o.x = pack2bf(a.x, a.y);
  o.y = pack2bf(a.z, a.w);
  o.z = pack2bf(b.x, b.y);
  o.w = pack2bf(b.z, b.w);
  *(uint4*)(enbf + idx) = o;
}

// emb[b,e,h] = sum_n node2edge[b,e,n] * node_state[b,n,h]   (fp32)
// block 128 thr: 4 edges x (32 lanes * float4 over h). grid (500, 2).
__global__ void k_n2e_emb(const float* __restrict__ n2e, const float* __restrict__ ns,
                          float* __restrict__ emb) {
  const int b = blockIdx.y;
  const int e = blockIdx.x * 4 + (threadIdx.x >> 5);
  const int c = (threadIdx.x & 31) * 4;
  const float* __restrict__ arow = n2e + ((size_t)b * Ev + e) * Nv;
  const float* __restrict__ sp = ns + (size_t)b * Nv * Hv + c;
  f32x4 acc = {0.f, 0.f, 0.f, 0.f};
#pragma unroll 4
  for (int n = 0; n < Nv; ++n) {
    float w = arow[n];
    f32x4 s = *(const f32x4*)(sp + (size_t)n * Hv);
    acc += w * s;
  }
  *(f32x4*)(emb + ((size_t)b * Ev + e) * Hv + c) = acc;
}

// norm[b,n] = 1 + sum_e edge2node[b,n,e]
__global__ void k_norm(const float* __restrict__ e2n, float* __restrict__ norm) {
  const int bn = blockIdx.x;
  const float* __restrict__ row = e2n + (size_t)bn * Ev;
  float acc = 0.f;
  for (int e = threadIdx.x; e < Ev; e += 256) acc += row[e];
#pragma unroll
  for (int off = 32; off > 0; off >>= 1) acc += __shfl_down(acc, off, 64);
  __shared__ float red[4];
  if ((threadIdx.x & 63) == 0) red[threadIdx.x >> 6] = acc;
  __syncthreads();
  if (threadIdx.x == 0) norm[bn] = red[0] + red[1] + red[2] + red[3] + 1.0f;
}

// new_n2e[m,i] += sum_{h in ksplit} sum_j (ev[m,h]*emb[m,j]) * EN[h,i,j]
// MFMA 16x16x32 bf16. Block: 128 m x 128 i, 8 h per block. Grid (32, 16).
// Wave tile: 4 m-tiles x 4 i-tiles (acc 16 x f32x4).
__launch_bounds__(256, 2)
__global__ void k_edge_mix(const float* __restrict__ ev, const float* __restrict__ emb,
                           const u16* __restrict__ enbf, float* __restrict__ newe) {
  __shared__ u16 U[128 * 136];  // u[m][j], row stride 136 bf16 (bank spread)
  const int t = threadIdx.x;
  const int lane = t & 63;
  const int w = t >> 6;
  const int row16 = lane & 15;
  const int kg = lane >> 4;
  const int mb = blockIdx.x * 128;
  const int h0 = blockIdx.y * 8;
  const int mtg = (w >> 1) * 4;
  const int itg = (w & 1) * 4;
  f32x4 acc[4][4];
#pragma unroll
  for (int i = 0; i < 4; ++i)
#pragma unroll
    for (int j = 0; j < 4; ++j) acc[i][j] = (f32x4){0.f, 0.f, 0.f, 0.f};

  for (int hh = 0; hh < 8; ++hh) {
    const int h = h0 + hh;
    __syncthreads();  // previous iter's LDS reads done before overwrite
    // stage u[m][j] = bf16(ev[mb+m][h] * emb[mb+m][j]); 64 elems/thread
#pragma unroll
    for (int r = 0; r < 8; ++r) {
      const int chunk = t + r * 256;
      const int m = chunk >> 4;
      const int jc = (chunk & 15) * 8;
      const int gm = mb + m;
      f32x4 x0 = {0.f,0.f,0.f,0.f}, x1 = {0.f,0.f,0.f,0.f};
      float evs = 0.f;
      if (gm < Mv) {
        evs = ev[(size_t)gm * Hv + h];
        const f32x4* p = (const f32x4*)(emb + (size_t)gm * Hv + jc);
        x0 = p[0]; x1 = p[1];
      }
      uint4 o;
      o.x = pack2bf(evs * x0.x, evs * x0.y);
      o.y = pack2bf(evs * x0.z, evs * x0.w);
      o.z = pack2bf(evs * x1.x, evs * x1.y);
      o.w = pack2bf(evs * x1.z, evs * x1.w);
      *(uint4*)&U[m * 136 + jc] = o;
    }
    __syncthreads();
    const u16* __restrict__ ben = enbf + (size_t)h * 16384;
#pragma unroll
    for (int kk = 0; kk < 4; ++kk) {
      bf16x8 a[4], bfr[4];
#pragma unroll
      for (int q = 0; q < 4; ++q) {
        const int mrow = (mtg + q) * 16 + row16;
        a[q] = *(const bf16x8*)&U[mrow * 136 + kk * 32 + kg * 8];
      }
#pragma unroll
      for (int q = 0; q < 4; ++q) {
        const int irow = (itg + q) * 16 + row16;
        bfr[q] = *(const bf16x8*)(ben + irow * 128 + kk * 32 + kg * 8);
      }
#pragma unroll
      for (int mi = 0; mi < 4; ++mi)
#pragma unroll
        for (int ii = 0; ii < 4; ++ii)
          acc[mi][ii] = __builtin_amdgcn_mfma_f32_16x16x32_bf16(a[mi], bfr[ii], acc[mi][ii], 0, 0, 0);
    }
  }
  // D layout: col = lane&15, row = (lane>>4)*4 + r
#pragma unroll
  for (int mi = 0; mi < 4; ++mi) {
#pragma unroll
    for (int r = 0; r < 4; ++r) {
      const int gm = mb + (mtg + mi) * 16 + kg * 4 + r;
      if (gm < Mv) {
#pragma unroll
        for (int ii = 0; ii < 4; ++ii)
          atomicAdd(&newe[(size_t)gm * Hv + (itg + ii) * 16 + row16], acc[mi][ii][r]);
      }
    }
  }
}

// agg[b,n,i] = (sum_e e2n[b,n,e]*newe[b,e,i] + ns[b,n,i]) / norm[b,n]
__global__ void k_agg(const float* __restrict__ e2n, const float* __restrict__ newe,
                      const float* __restrict__ ns, const float* __restrict__ norm,
                      float* __restrict__ out) {
  const int b = blockIdx.y;
  const int n = blockIdx.x * 4 + (threadIdx.x >> 5);
  const int c = (threadIdx.x & 31) * 4;
  const float* __restrict__ wrow = e2n + ((size_t)b * Nv + n) * Ev;
  const float* __restrict__ vp = newe + (size_t)b * Ev * Hv + c;
  f32x4 acc = {0.f, 0.f, 0.f, 0.f};
#pragma unroll 4
  for (int e = 0; e < Ev; ++e) {
    float wv = wrow[e];
    f32x4 v = *(const f32x4*)(vp + (size_t)e * Hv);
    acc += wv * v;
  }
  const size_t o = ((size_t)b * Nv + n) * Hv + c;
  f32x4 s = *(const f32x4*)(ns + o);
  float nm = norm[(size_t)b * Nv + n];
  f32x4 res = (acc + s) / nm;
  *(f32x4*)(out + o) = res;
}

extern "C" void kernel_launch(void* const* d_in, const int* in_sizes, int n_in,
                              void* d_out, int out_size, void* d_ws, size_t ws_size,
                              hipStream_t stream) {
  const float* ns  = (const float*)d_in[0];  // node_state  [B][N][H]
  const float* ev  = (const float*)d_in[1];  // edge_vec    [B][E][H]
  const float* n2e = (const float*)d_in[2];  // node2edge   [B][E][N]
  const float* e2n = (const float*)d_in[3];  // edge2node   [B][N][E]
  const float* en  = (const float*)d_in[4];  // edge_network[H][H][H]
  float* out = (float*)d_out;

  char* ws = (char*)d_ws;
  float* emb  = (float*)(ws);                 // [4000][128] fp32, 2,048,000 B
  float* newe = (float*)(ws + 2048000);       // [4000][128] fp32, 2,048,000 B
  u16*   enbf = (u16*)  (ws + 4096000);       // [128][128][128] bf16, 4,194,304 B
  float* norm = (float*)(ws + 8290304);       // [2000] fp32

  hipMemsetAsync(newe, 0, 2048000, stream);   // atomic accumulation target
  k_cvt_en <<<dim3(1024),    dim3(256), 0, stream>>>(en, enbf);
  k_n2e_emb<<<dim3(500, 2),  dim3(128), 0, stream>>>(n2e, ns, emb);
  k_norm   <<<dim3(2000),    dim3(256), 0, stream>>>(e2n, norm);
  k_edge_mix<<<dim3(32, 16), dim3(256), 0, stream>>>(ev, emb, enbf, newe);
  k_agg    <<<dim3(250, 2),  dim3(128), 0, stream>>>(e2n, newe, ns, norm, out);
}

// Round 2
// 191.451 us; speedup vs baseline: 1.5931x; 1.5931x over previous
//
#include <hip/hip_runtime.h>
#include <hip/hip_bf16.h>
#include <stdint.h>

#define Bv 2
#define Nv 1000
#define Ev 2000
#define Hv 128
#define Mv 4000  // Bv*Ev

typedef __attribute__((ext_vector_type(8))) short bf16x8;
typedef __attribute__((ext_vector_type(4))) float f32x4;
typedef unsigned short u16;
typedef unsigned int u32;

static __device__ __forceinline__ u32 pack2bf(float a, float b) {
  union { __hip_bfloat162 h; u32 u; } c;
  c.h = __float22bfloat162_rn(make_float2(a, b));
  return c.u;
}
static __device__ __forceinline__ u16 cvt1bf(float a) {
  return (u16)(pack2bf(a, 0.f) & 0xffffu);
}

// edge_network fp32 [H][H][H] -> bf16, same (h,i,j) layout. 2M elems, 8/thread.
__global__ void k_cvt_en(const float* __restrict__ en, u16* __restrict__ enbf) {
  size_t idx = ((size_t)blockIdx.x * 256u + threadIdx.x) * 8u;
  const f32x4* p = (const f32x4*)(en + idx);
  f32x4 a = p[0], b = p[1];
  uint4 o;
  o.x = pack2bf(a.x, a.y);
  o.y = pack2bf(a.z, a.w);
  o.z = pack2bf(b.x, b.y);
  o.w = pack2bf(b.z, b.w);
  *(uint4*)(enbf + idx) = o;
}

// Transpose+convert: src fp32 [R][C] -> dst bf16 [C][Rpad], zero-filled rows R..Rpad.
// grid (Rpad/32, C/32, batches), block 256.
__global__ void k_tr_cvt(const float* __restrict__ src, u16* __restrict__ dst,
                         int R, int C, int Rpad) {
  __shared__ float tile[32][33];
  const int z = blockIdx.z;
  src += (size_t)z * R * C;
  dst += (size_t)z * C * Rpad;
  const int r0 = blockIdx.x * 32, c0 = blockIdx.y * 32;
  const int tx = threadIdx.x & 31, ty = threadIdx.x >> 5;
#pragma unroll
  for (int rr = 0; rr < 4; ++rr) {
    int r = r0 + ty + rr * 8;
    int c = c0 + tx;
    float v = (r < R && c < C) ? src[(size_t)r * C + c] : 0.f;
    tile[ty + rr * 8][tx] = v;
  }
  __syncthreads();
#pragma unroll
  for (int rr = 0; rr < 4; ++rr) {
    int oc = c0 + ty + rr * 8;  // dst row = src col
    int orr = r0 + tx;          // dst col = src row
    if (oc < C)
      dst[(size_t)oc * Rpad + orr] = cvt1bf(tile[tx][ty + rr * 8]);
  }
}

// C[m,i] = sum_k A[m,k] * BT[i,k]  (bf16 MFMA 16x16x32, fp32 acc)
// A fp32 row-major [M][KREAL] per batch; BT bf16 [128][KPAD] per batch (zero-padded).
// AGG epilogue: out = (C + ns)/ (1 + rowsum(A)); rowsum fused into staging.
template <int M, int KREAL, int KPAD, bool AGG>
__launch_bounds__(256, 2)
__global__ void k_gemm_bt(const float* __restrict__ A, const u16* __restrict__ BT,
                          float* __restrict__ Cout, const float* __restrict__ nsp) {
  __shared__ u16 AL[64 * 136];
  __shared__ float rowsum[64];
  const int b = blockIdx.y;
  A    += (size_t)b * M * KREAL;
  BT   += (size_t)b * 128 * KPAD;
  Cout += (size_t)b * M * 128;
  if (AGG) nsp += (size_t)b * M * 128;
  const int t = threadIdx.x;
  const int lane = t & 63;
  const int w = t >> 6;
  const int row16 = lane & 15;
  const int kg = lane >> 4;
  const int mrow0 = blockIdx.x * 64;
  const int mtg = (w >> 1) * 2;  // m-frag base (2 frags per wave)
  const int itg = (w & 1) * 4;   // i-frag base (4 frags per wave)
  f32x4 acc[2][4];
#pragma unroll
  for (int i = 0; i < 2; ++i)
#pragma unroll
    for (int j = 0; j < 4; ++j) acc[i][j] = (f32x4){0.f, 0.f, 0.f, 0.f};
  if (AGG && t < 64) rowsum[t] = 0.f;

  for (int kc = 0; kc < KPAD; kc += 128) {
    __syncthreads();
    // stage A[mrow0..+64][kc..+128] fp32 -> bf16 LDS (stride 136)
#pragma unroll
    for (int r = 0; r < 4; ++r) {
      const int chunk = t + r * 256;
      const int m = chunk >> 4;
      const int jc = (chunk & 15) * 8;
      const int gm = mrow0 + m;
      const int gk = kc + jc;
      f32x4 x0 = {0.f, 0.f, 0.f, 0.f}, x1 = {0.f, 0.f, 0.f, 0.f};
      if (gm < M && gk + 8 <= KREAL) {  // KREAL % 8 == 0 always here
        const f32x4* p = (const f32x4*)(A + (size_t)gm * KREAL + gk);
        x0 = p[0];
        x1 = p[1];
      }
      if (AGG) {
        float s8 = x0.x + x0.y + x0.z + x0.w + x1.x + x1.y + x1.z + x1.w;
        s8 += __shfl_down(s8, 8, 16);
        s8 += __shfl_down(s8, 4, 16);
        s8 += __shfl_down(s8, 2, 16);
        s8 += __shfl_down(s8, 1, 16);
        if ((lane & 15) == 0) rowsum[m] += s8;  // unique m per 16-lane group
      }
      uint4 o;
      o.x = pack2bf(x0.x, x0.y);
      o.y = pack2bf(x0.z, x0.w);
      o.z = pack2bf(x1.x, x1.y);
      o.w = pack2bf(x1.z, x1.w);
      *(uint4*)&AL[m * 136 + jc] = o;
    }
    __syncthreads();
#pragma unroll
    for (int kk = 0; kk < 4; ++kk) {
      bf16x8 a[2], bfr[4];
#pragma unroll
      for (int q = 0; q < 2; ++q)
        a[q] = *(const bf16x8*)&AL[((mtg + q) * 16 + row16) * 136 + kk * 32 + kg * 8];
#pragma unroll
      for (int q = 0; q < 4; ++q)
        bfr[q] = *(const bf16x8*)(BT + (size_t)((itg + q) * 16 + row16) * KPAD + kc + kk * 32 + kg * 8);
#pragma unroll
      for (int mi = 0; mi < 2; ++mi)
#pragma unroll
        for (int ii = 0; ii < 4; ++ii)
          acc[mi][ii] = __builtin_amdgcn_mfma_f32_16x16x32_bf16(a[mi], bfr[ii], acc[mi][ii], 0, 0, 0);
    }
  }
  // D layout: col = lane&15, row = kg*4 + r
#pragma unroll
  for (int mi = 0; mi < 2; ++mi) {
#pragma unroll
    for (int r = 0; r < 4; ++r) {
      const int lrow = (mtg + mi) * 16 + kg * 4 + r;
      const int gm = mrow0 + lrow;
      if (gm < M) {
        float inv = 1.f;
        if (AGG) inv = 1.f / (rowsum[lrow] + 1.0f);
#pragma unroll
        for (int ii = 0; ii < 4; ++ii) {
          const int col = (itg + ii) * 16 + row16;
          float v = acc[mi][ii][r];
          if (AGG) v = (v + nsp[(size_t)gm * 128 + col]) * inv;
          Cout[(size_t)gm * 128 + col] = v;
        }
      }
    }
  }
}

// new_n2e[m,i] += sum_{h in ksplit} sum_j (ev[m,h]*emb[m,j]) * EN[h,i,j]
// MFMA 16x16x32 bf16. Block: 128 m x 128 i, 8 h per block. Grid (32, 16).
__launch_bounds__(256, 2)
__global__ void k_edge_mix(const float* __restrict__ ev, const float* __restrict__ emb,
                           const u16* __restrict__ enbf, float* __restrict__ newe) {
  __shared__ u16 U[128 * 136];  // u[m][j], row stride 136 bf16 (bank spread)
  const int t = threadIdx.x;
  const int lane = t & 63;
  const int w = t >> 6;
  const int row16 = lane & 15;
  const int kg = lane >> 4;
  const int mb = blockIdx.x * 128;
  const int h0 = blockIdx.y * 8;
  const int mtg = (w >> 1) * 4;
  const int itg = (w & 1) * 4;
  f32x4 acc[4][4];
#pragma unroll
  for (int i = 0; i < 4; ++i)
#pragma unroll
    for (int j = 0; j < 4; ++j) acc[i][j] = (f32x4){0.f, 0.f, 0.f, 0.f};

  for (int hh = 0; hh < 8; ++hh) {
    const int h = h0 + hh;
    __syncthreads();
#pragma unroll
    for (int r = 0; r < 8; ++r) {
      const int chunk = t + r * 256;
      const int m = chunk >> 4;
      const int jc = (chunk & 15) * 8;
      const int gm = mb + m;
      f32x4 x0 = {0.f,0.f,0.f,0.f}, x1 = {0.f,0.f,0.f,0.f};
      float evs = 0.f;
      if (gm < Mv) {
        evs = ev[(size_t)gm * Hv + h];
        const f32x4* p = (const f32x4*)(emb + (size_t)gm * Hv + jc);
        x0 = p[0]; x1 = p[1];
      }
      uint4 o;
      o.x = pack2bf(evs * x0.x, evs * x0.y);
      o.y = pack2bf(evs * x0.z, evs * x0.w);
      o.z = pack2bf(evs * x1.x, evs * x1.y);
      o.w = pack2bf(evs * x1.z, evs * x1.w);
      *(uint4*)&U[m * 136 + jc] = o;
    }
    __syncthreads();
    const u16* __restrict__ ben = enbf + (size_t)h * 16384;
#pragma unroll
    for (int kk = 0; kk < 4; ++kk) {
      bf16x8 a[4], bfr[4];
#pragma unroll
      for (int q = 0; q < 4; ++q) {
        const int mrow = (mtg + q) * 16 + row16;
        a[q] = *(const bf16x8*)&U[mrow * 136 + kk * 32 + kg * 8];
      }
#pragma unroll
      for (int q = 0; q < 4; ++q) {
        const int irow = (itg + q) * 16 + row16;
        bfr[q] = *(const bf16x8*)(ben + irow * 128 + kk * 32 + kg * 8);
      }
#pragma unroll
      for (int mi = 0; mi < 4; ++mi)
#pragma unroll
        for (int ii = 0; ii < 4; ++ii)
          acc[mi][ii] = __builtin_amdgcn_mfma_f32_16x16x32_bf16(a[mi], bfr[ii], acc[mi][ii], 0, 0, 0);
    }
  }
#pragma unroll
  for (int mi = 0; mi < 4; ++mi) {
#pragma unroll
    for (int r = 0; r < 4; ++r) {
      const int gm = mb + (mtg + mi) * 16 + kg * 4 + r;
      if (gm < Mv) {
#pragma unroll
        for (int ii = 0; ii < 4; ++ii)
          atomicAdd(&newe[(size_t)gm * Hv + (itg + ii) * 16 + row16], acc[mi][ii][r]);
      }
    }
  }
}

extern "C" void kernel_launch(void* const* d_in, const int* in_sizes, int n_in,
                              void* d_out, int out_size, void* d_ws, size_t ws_size,
                              hipStream_t stream) {
  const float* ns  = (const float*)d_in[0];  // node_state  [B][N][H]
  const float* ev  = (const float*)d_in[1];  // edge_vec    [B][E][H]
  const float* n2e = (const float*)d_in[2];  // node2edge   [B][E][N]
  const float* e2n = (const float*)d_in[3];  // edge2node   [B][N][E]
  const float* en  = (const float*)d_in[4];  // edge_network[H][H][H]
  float* out = (float*)d_out;

  char* ws = (char*)d_ws;
  float* newe  = (float*)(ws);                 // [4000][128] fp32, 2,048,000 B
  u16*   enbf  = (u16*)  (ws + 2048000);       // [128][128][128] bf16, 4,194,304 B
  u16*   nsT   = (u16*)  (ws + 6242304);       // [2][128][1024] bf16, 524,288 B
  float* emb   = (float*)(ws + 6766592);       // [4000][128] fp32, 2,048,000 B
  u16*   neweT = (u16*)  (ws + 6766592);       // [2][128][2048] bf16 (overlaps emb; emb dead by then)

  hipMemsetAsync(newe, 0, 2048000, stream);    // atomic accumulation target
  k_cvt_en <<<dim3(1024),     dim3(256), 0, stream>>>(en, enbf);
  k_tr_cvt <<<dim3(32, 4, 2), dim3(256), 0, stream>>>(ns, nsT, Nv, Hv, 1024);
  // emb[b,e,:] = n2e[b,e,:] @ ns[b]   (M=2000, K=1000)
  k_gemm_bt<2000, 1000, 1024, false><<<dim3(32, 2), dim3(256), 0, stream>>>(n2e, nsT, emb, nullptr);
  k_edge_mix<<<dim3(32, 16), dim3(256), 0, stream>>>(ev, emb, enbf, newe);
  k_tr_cvt <<<dim3(64, 4, 2), dim3(256), 0, stream>>>(newe, neweT, Ev, Hv, 2048);
  // out[b,n,:] = (e2n[b,n,:] @ newe[b] + ns[b,n,:]) / (1 + rowsum(e2n[b,n,:]))  (M=1000, K=2000)
  k_gemm_bt<1000, 2000, 2048, true><<<dim3(16, 2), dim3(256), 0, stream>>>(e2n, neweT, out, ns);
}

// Round 3
// 140.063 us; speedup vs baseline: 2.1776x; 1.3669x over previous
//
#include <hip/hip_runtime.h>
#include <hip/hip_bf16.h>
#include <stdint.h>

#define Bv 2
#define Nv 1000
#define Ev 2000
#define Hv 128
#define Mv 4000  // Bv*Ev

typedef __attribute__((ext_vector_type(8))) short bf16x8;
typedef __attribute__((ext_vector_type(4))) float f32x4;
typedef unsigned short u16;
typedef unsigned int u32;

static __device__ __forceinline__ u32 pack2bf(float a, float b) {
  union { __hip_bfloat162 h; u32 u; } c;
  c.h = __float22bfloat162_rn(make_float2(a, b));
  return c.u;
}
static __device__ __forceinline__ u16 cvt1bf(float a) {
  return (u16)(pack2bf(a, 0.f) & 0xffffu);
}

// edge_network fp32 [H][H][H] -> bf16, same (h,i,j) layout. 2M elems, 8/thread.
__global__ void k_cvt_en(const float* __restrict__ en, u16* __restrict__ enbf) {
  size_t idx = ((size_t)blockIdx.x * 256u + threadIdx.x) * 8u;
  const f32x4* p = (const f32x4*)(en + idx);
  f32x4 a = p[0], b = p[1];
  uint4 o;
  o.x = pack2bf(a.x, a.y);
  o.y = pack2bf(a.z, a.w);
  o.z = pack2bf(b.x, b.y);
  o.w = pack2bf(b.z, b.w);
  *(uint4*)(enbf + idx) = o;
}

// Transpose+convert: src fp32 [R][C] -> dst bf16 [C][Rpad], zero-filled rows R..Rpad.
// grid (Rpad/32, C/32, batches), block 256.
__global__ void k_tr_cvt(const float* __restrict__ src, u16* __restrict__ dst,
                         int R, int C, int Rpad) {
  __shared__ float tile[32][33];
  const int z = blockIdx.z;
  src += (size_t)z * R * C;
  dst += (size_t)z * C * Rpad;
  const int r0 = blockIdx.x * 32, c0 = blockIdx.y * 32;
  const int tx = threadIdx.x & 31, ty = threadIdx.x >> 5;
#pragma unroll
  for (int rr = 0; rr < 4; ++rr) {
    int r = r0 + ty + rr * 8;
    int c = c0 + tx;
    float v = (r < R && c < C) ? src[(size_t)r * C + c] : 0.f;
    tile[ty + rr * 8][tx] = v;
  }
  __syncthreads();
#pragma unroll
  for (int rr = 0; rr < 4; ++rr) {
    int oc = c0 + ty + rr * 8;  // dst row = src col
    int orr = r0 + tx;          // dst col = src row
    if (oc < C)
      dst[(size_t)oc * Rpad + orr] = cvt1bf(tile[tx][ty + rr * 8]);
  }
}

// Split-K GEMM partial: Cacc[m,i] += sum_{k in chunk} A[m,k]*BT[i,k]
// grid (ceil(M/64), KPAD/128, B). One 128-wide K-chunk per block, fp32 atomic out.
// ROWSUM: also nrmacc[m] += sum_{k in chunk} A[m,k]  (for the agg normalizer).
template <int M, int KREAL, int KPAD, bool ROWSUM>
__launch_bounds__(256, 4)
__global__ void k_gemm_split(const float* __restrict__ A, const u16* __restrict__ BT,
                             float* __restrict__ Cacc, float* __restrict__ nrmacc) {
  __shared__ u16 AL[64 * 136];
  __shared__ float rowsum[64];
  const int b = blockIdx.z;
  A    += (size_t)b * M * KREAL;
  BT   += (size_t)b * 128 * KPAD;
  Cacc += (size_t)b * M * 128;
  if (ROWSUM) nrmacc += (size_t)b * M;
  const int t = threadIdx.x;
  const int lane = t & 63;
  const int w = t >> 6;
  const int row16 = lane & 15;
  const int kg = lane >> 4;
  const int mrow0 = blockIdx.x * 64;
  const int kc = blockIdx.y * 128;
  const int mtg = (w >> 1) * 2;  // m-frag base (2 frags per wave)
  const int itg = (w & 1) * 4;   // i-frag base (4 frags per wave)
  f32x4 acc[2][4];
#pragma unroll
  for (int i = 0; i < 2; ++i)
#pragma unroll
    for (int j = 0; j < 4; ++j) acc[i][j] = (f32x4){0.f, 0.f, 0.f, 0.f};
  if (ROWSUM && t < 64) rowsum[t] = 0.f;
  __syncthreads();
  // stage A[mrow0..+64][kc..+128] fp32 -> bf16 LDS (stride 136)
#pragma unroll
  for (int r = 0; r < 4; ++r) {
    const int chunk = t + r * 256;
    const int m = chunk >> 4;
    const int jc = (chunk & 15) * 8;
    const int gm = mrow0 + m;
    const int gk = kc + jc;
    f32x4 x0 = {0.f, 0.f, 0.f, 0.f}, x1 = {0.f, 0.f, 0.f, 0.f};
    if (gm < M && gk + 8 <= KREAL) {  // KREAL % 8 == 0 here
      const f32x4* p = (const f32x4*)(A + (size_t)gm * KREAL + gk);
      x0 = p[0];
      x1 = p[1];
    }
    if (ROWSUM) {
      float s8 = x0.x + x0.y + x0.z + x0.w + x1.x + x1.y + x1.z + x1.w;
      s8 += __shfl_down(s8, 8, 16);
      s8 += __shfl_down(s8, 4, 16);
      s8 += __shfl_down(s8, 2, 16);
      s8 += __shfl_down(s8, 1, 16);
      if ((lane & 15) == 0) rowsum[m] += s8;  // unique m per 16-lane group
    }
    uint4 o;
    o.x = pack2bf(x0.x, x0.y);
    o.y = pack2bf(x0.z, x0.w);
    o.z = pack2bf(x1.x, x1.y);
    o.w = pack2bf(x1.z, x1.w);
    *(uint4*)&AL[m * 136 + jc] = o;
  }
  __syncthreads();
#pragma unroll
  for (int kk = 0; kk < 4; ++kk) {
    bf16x8 a[2], bfr[4];
#pragma unroll
    for (int q = 0; q < 2; ++q)
      a[q] = *(const bf16x8*)&AL[((mtg + q) * 16 + row16) * 136 + kk * 32 + kg * 8];
#pragma unroll
    for (int q = 0; q < 4; ++q)
      bfr[q] = *(const bf16x8*)(BT + (size_t)((itg + q) * 16 + row16) * KPAD + kc + kk * 32 + kg * 8);
#pragma unroll
    for (int mi = 0; mi < 2; ++mi)
#pragma unroll
      for (int ii = 0; ii < 4; ++ii)
        acc[mi][ii] = __builtin_amdgcn_mfma_f32_16x16x32_bf16(a[mi], bfr[ii], acc[mi][ii], 0, 0, 0);
  }
  if (ROWSUM && t < 64 && mrow0 + t < M) atomicAdd(&nrmacc[mrow0 + t], rowsum[t]);
  // D layout: col = lane&15, row = kg*4 + r
#pragma unroll
  for (int mi = 0; mi < 2; ++mi) {
#pragma unroll
    for (int r = 0; r < 4; ++r) {
      const int lrow = (mtg + mi) * 16 + kg * 4 + r;
      const int gm = mrow0 + lrow;
      if (gm < M) {
#pragma unroll
        for (int ii = 0; ii < 4; ++ii)
          atomicAdd(&Cacc[(size_t)gm * 128 + (itg + ii) * 16 + row16], acc[mi][ii][r]);
      }
    }
  }
}

// out = (aggacc + ns) / (norm + 1), 2*1000*128 elems, f32x4 per thread.
__global__ void k_epi(const float* __restrict__ acc, const float* __restrict__ ns,
                      const float* __restrict__ nrm, float* __restrict__ out) {
  const int idx = (blockIdx.x * 256 + threadIdx.x) * 4;
  f32x4 a = *(const f32x4*)(acc + idx);
  f32x4 s = *(const f32x4*)(ns + idx);
  const int row = idx >> 7;  // b*1000+n
  float inv = 1.f / (nrm[row] + 1.0f);
  *(f32x4*)(out + idx) = (a + s) * inv;
}

// new_n2e[m,i] += sum_{h in ksplit} sum_j (ev[m,h]*emb[m,j]) * EN[h,i,j]
// MFMA 16x16x32 bf16. Block: 128 m x 128 i, 8 h per block. Grid (32, 16).
__launch_bounds__(256, 2)
__global__ void k_edge_mix(const float* __restrict__ ev, const float* __restrict__ emb,
                           const u16* __restrict__ enbf, float* __restrict__ newe) {
  __shared__ u16 U[128 * 136];  // u[m][j], row stride 136 bf16 (bank spread)
  const int t = threadIdx.x;
  const int lane = t & 63;
  const int w = t >> 6;
  const int row16 = lane & 15;
  const int kg = lane >> 4;
  const int mb = blockIdx.x * 128;
  const int h0 = blockIdx.y * 8;
  const int mtg = (w >> 1) * 4;
  const int itg = (w & 1) * 4;
  f32x4 acc[4][4];
#pragma unroll
  for (int i = 0; i < 4; ++i)
#pragma unroll
    for (int j = 0; j < 4; ++j) acc[i][j] = (f32x4){0.f, 0.f, 0.f, 0.f};

  for (int hh = 0; hh < 8; ++hh) {
    const int h = h0 + hh;
    __syncthreads();
#pragma unroll
    for (int r = 0; r < 8; ++r) {
      const int chunk = t + r * 256;
      const int m = chunk >> 4;
      const int jc = (chunk & 15) * 8;
      const int gm = mb + m;
      f32x4 x0 = {0.f,0.f,0.f,0.f}, x1 = {0.f,0.f,0.f,0.f};
      float evs = 0.f;
      if (gm < Mv) {
        evs = ev[(size_t)gm * Hv + h];
        const f32x4* p = (const f32x4*)(emb + (size_t)gm * Hv + jc);
        x0 = p[0]; x1 = p[1];
      }
      uint4 o;
      o.x = pack2bf(evs * x0.x, evs * x0.y);
      o.y = pack2bf(evs * x0.z, evs * x0.w);
      o.z = pack2bf(evs * x1.x, evs * x1.y);
      o.w = pack2bf(evs * x1.z, evs * x1.w);
      *(uint4*)&U[m * 136 + jc] = o;
    }
    __syncthreads();
    const u16* __restrict__ ben = enbf + (size_t)h * 16384;
#pragma unroll
    for (int kk = 0; kk < 4; ++kk) {
      bf16x8 a[4], bfr[4];
#pragma unroll
      for (int q = 0; q < 4; ++q) {
        const int mrow = (mtg + q) * 16 + row16;
        a[q] = *(const bf16x8*)&U[mrow * 136 + kk * 32 + kg * 8];
      }
#pragma unroll
      for (int q = 0; q < 4; ++q) {
        const int irow = (itg + q) * 16 + row16;
        bfr[q] = *(const bf16x8*)(ben + irow * 128 + kk * 32 + kg * 8);
      }
#pragma unroll
      for (int mi = 0; mi < 4; ++mi)
#pragma unroll
        for (int ii = 0; ii < 4; ++ii)
          acc[mi][ii] = __builtin_amdgcn_mfma_f32_16x16x32_bf16(a[mi], bfr[ii], acc[mi][ii], 0, 0, 0);
    }
  }
#pragma unroll
  for (int mi = 0; mi < 4; ++mi) {
#pragma unroll
    for (int r = 0; r < 4; ++r) {
      const int gm = mb + (mtg + mi) * 16 + kg * 4 + r;
      if (gm < Mv) {
#pragma unroll
        for (int ii = 0; ii < 4; ++ii)
          atomicAdd(&newe[(size_t)gm * Hv + (itg + ii) * 16 + row16], acc[mi][ii][r]);
      }
    }
  }
}

extern "C" void kernel_launch(void* const* d_in, const int* in_sizes, int n_in,
                              void* d_out, int out_size, void* d_ws, size_t ws_size,
                              hipStream_t stream) {
  const float* ns  = (const float*)d_in[0];  // node_state  [B][N][H]
  const float* ev  = (const float*)d_in[1];  // edge_vec    [B][E][H]
  const float* n2e = (const float*)d_in[2];  // node2edge   [B][E][N]
  const float* e2n = (const float*)d_in[3];  // edge2node   [B][N][E]
  const float* en  = (const float*)d_in[4];  // edge_network[H][H][H]
  float* out = (float*)d_out;

  char* ws = (char*)d_ws;
  // Live ranges allow heavy overlay:
  float* embacc  = (float*)(ws);              // [4000][128] f32 (2,048,000 B)  — dead after edge_mix
  float* newe    = (float*)(ws + 2048000);    // [4000][128] f32 (2,048,000 B)
  float* normacc = (float*)(ws + 4096000);    // [2][1000] f32 (8,192 B pad)
  u16*   enbf    = (u16*)  (ws + 4104192);    // [128][128][128] bf16 (4,194,304 B) — dead after edge_mix
  u16*   nsT     = (u16*)  (ws + 8298496);    // [2][128][1024] bf16 (524,288 B)
  u16*   neweT   = (u16*)  (ws);              // [2][128][2048] bf16 (1,048,576 B) — overlays embacc
  float* aggacc  = (float*)(ws + 4104192);    // [2][1000][128] f32 (1,024,000 B) — overlays enbf

  // zero embacc + newe + normacc in one shot
  hipMemsetAsync(ws, 0, 4104192, stream);
  k_cvt_en <<<dim3(1024),     dim3(256), 0, stream>>>(en, enbf);
  k_tr_cvt <<<dim3(32, 4, 2), dim3(256), 0, stream>>>(ns, nsT, Nv, Hv, 1024);
  // emb[b,e,:] = n2e[b,e,:] @ ns[b]   (M=2000, K=1000, split-K x8)
  k_gemm_split<2000, 1000, 1024, false><<<dim3(32, 8, 2), dim3(256), 0, stream>>>(n2e, nsT, embacc, nullptr);
  k_edge_mix<<<dim3(32, 16), dim3(256), 0, stream>>>(ev, embacc, enbf, newe);
  hipMemsetAsync(aggacc, 0, 1024000, stream);           // enbf dead now
  k_tr_cvt <<<dim3(64, 4, 2), dim3(256), 0, stream>>>(newe, neweT, Ev, Hv, 2048);
  // aggacc[b,n,:] += e2n[b,n,:] @ newe[b]  (M=1000, K=2000, split-K x16) + rowsum->normacc
  k_gemm_split<1000, 2000, 2048, true><<<dim3(16, 16, 2), dim3(256), 0, stream>>>(e2n, neweT, aggacc, normacc);
  k_epi<<<dim3(250), dim3(256), 0, stream>>>(aggacc, ns, normacc, out);
}